// Round 3
// baseline (321.079 us; speedup 1.0000x reference)
//
#include <hip/hip_runtime.h>
#include <hip/hip_bf16.h>

// EnhancedCondConv2d: B=32, CI=128, CO=256, H=W=64, E=8, R=16, K=3
// R7: k_conv2p — 256x256 tile, BK=64, 8 waves, minimum 2-phase schedule:
//     stage(t+1 -> other buf) BEFORE compute(t), one __syncthreads() per
//     K-tile (full vmcnt/lgkm drain). Indexing formulas bit-identical to
//     R5/R6; ALL raw-asm barrier machinery removed. This bisects the
//     R5/R6 deterministic failure: pass => indexing good (bug was phase
//     machinery); fail => indexing bug (revert to R4). Other kernels
//     identical to R4.

#define BB 32
#define CI_ 128
#define CO_ 256
#define HW_ 4096
#define KK 1152   // CI*9

typedef unsigned short u16;
typedef __attribute__((ext_vector_type(8))) __bf16 bf16x8;
typedef __attribute__((ext_vector_type(4))) float floatx4;

typedef const __attribute__((address_space(1))) void* gptr_t;
typedef __attribute__((address_space(3))) void* sptr_t;

__device__ __forceinline__ void gload_lds16(const void* g, void* s) {
  __builtin_amdgcn_global_load_lds((gptr_t)g, (sptr_t)s, 16, 0, 0);
}

// ---------------- k_stats2: per-(b,ci) plane statistics ----------------
__global__ __launch_bounds__(256) void k_stats2(const float* __restrict__ x,
                                                float* __restrict__ Sr,
                                                float* __restrict__ pooled,
                                                unsigned* __restrict__ zp) {
  int blk = blockIdx.x;
  int tid = threadIdx.x;
  if (blk == 0 && tid < 64) zp[tid] = 0u;  // 256B zero page
  int b = blk >> 7, ci = blk & 127;
  const float4* xp = (const float4*)(x + ((size_t)(b * CI_ + ci) << 12));
  float T = 0.f, r0 = 0.f, r63 = 0.f, c0 = 0.f, c63 = 0.f;
  __shared__ float corn[4];
  __shared__ float wsum[4][5];
#pragma unroll
  for (int j = 0; j < 4; j++) {
    int idx = j * 256 + tid;
    float4 v = xp[idx];
    float rs = v.x + v.y + v.z + v.w;
    T += rs;
    int x16 = idx & 15;
    if (idx < 16)    r0  += rs;
    if (idx >= 1008) r63 += rs;
    if (x16 == 0)  c0  += v.x;
    if (x16 == 15) c63 += v.w;
    if (idx == 0)    corn[0] = v.x;
    if (idx == 15)   corn[1] = v.w;
    if (idx == 1008) corn[2] = v.x;
    if (idx == 1023) corn[3] = v.w;
  }
  for (int off = 32; off; off >>= 1) {
    T   += __shfl_down(T, off);
    r0  += __shfl_down(r0, off);
    r63 += __shfl_down(r63, off);
    c0  += __shfl_down(c0, off);
    c63 += __shfl_down(c63, off);
  }
  int w = tid >> 6, lane = tid & 63;
  if (lane == 0) { wsum[w][0]=T; wsum[w][1]=r0; wsum[w][2]=r63; wsum[w][3]=c0; wsum[w][4]=c63; }
  __syncthreads();
  if (tid == 0) {
    T   = wsum[0][0]+wsum[1][0]+wsum[2][0]+wsum[3][0];
    r0  = wsum[0][1]+wsum[1][1]+wsum[2][1]+wsum[3][1];
    r63 = wsum[0][2]+wsum[1][2]+wsum[2][2]+wsum[3][2];
    c0  = wsum[0][3]+wsum[1][3]+wsum[2][3]+wsum[3][3];
    c63 = wsum[0][4]+wsum[1][4]+wsum[2][4]+wsum[3][4];
    pooled[b * CI_ + ci] = T * (1.0f / 4096.0f);
#pragma unroll
    for (int ky = 0; ky < 3; ky++) {
#pragma unroll
      for (int kx = 0; kx < 3; kx++) {
        int dy = ky - 1, dx = kx - 1;
        float s = T;
        if (dy == -1) s -= r63;
        if (dy ==  1) s -= r0;
        if (dx == -1) s -= c63;
        if (dx ==  1) s -= c0;
        if (dy != 0 && dx != 0) s += corn[(dy == -1 ? 2 : 0) + (dx == -1 ? 1 : 0)];
        Sr[(b * 9 + ky * 3 + kx) * CI_ + ci] = s * (1.0f / 4096.0f);
      }
    }
  }
}

// ---------------- k_xform: NCHW f32 -> NHWC bf16 (vectorized) ----------------
__global__ __launch_bounds__(256) void k_xform(const float* __restrict__ x,
                                               u16* __restrict__ xt) {
  int blk = blockIdx.x;          // b*64 + y
  int b = blk >> 6, y = blk & 63;
  __shared__ u16 ts[64][132];
  int tid = threadIdx.x;
  const float* xb = x + ((size_t)b << 19) + (y << 6);
#pragma unroll
  for (int it = 0; it < 8; it++) {
    int idx = it * 256 + tid;
    int ci = idx >> 4, x4 = idx & 15;
    float4 v = *(const float4*)(xb + (size_t)ci * 4096 + x4 * 4);
    __hip_bfloat16 h0 = __float2bfloat16(v.x), h1 = __float2bfloat16(v.y);
    __hip_bfloat16 h2 = __float2bfloat16(v.z), h3 = __float2bfloat16(v.w);
    int xx = x4 << 2;
    ts[xx + 0][ci] = *(const u16*)&h0;
    ts[xx + 1][ci] = *(const u16*)&h1;
    ts[xx + 2][ci] = *(const u16*)&h2;
    ts[xx + 3][ci] = *(const u16*)&h3;
  }
  __syncthreads();
  uint2* ot = (uint2*)(xt + ((size_t)b * HW_ + y * 64) * CI_);
#pragma unroll
  for (int it = 0; it < 8; it++) {
    int o = it * 256 + tid;
    int pix = o >> 5, c4 = o & 31;
    ot[o] = *(const uint2*)&ts[pix][c4 * 4];
  }
}

// ---------------- k_route2: SE gate -> softmax (parallel dots) ----------------
__global__ __launch_bounds__(128) void k_route2(const float* __restrict__ pooled,
    const float* __restrict__ rw1, const float* __restrict__ rb1,
    const float* __restrict__ rw2, const float* __restrict__ rb2,
    const float* __restrict__ rw3, const float* __restrict__ rb3,
    float* __restrict__ r) {
  int b = blockIdx.x, tid = threadIdx.x;
  int o = tid >> 4, l = tid & 15;
  __shared__ float ps[128], hs[8], ss[128], lg[8];
  ps[tid] = pooled[b * 128 + tid];
  __syncthreads();
  {
    float a = 0.f;
#pragma unroll
    for (int j = 0; j < 8; j++) a += ps[l * 8 + j] * rw1[o * 128 + l * 8 + j];
    a += __shfl_xor(a, 1); a += __shfl_xor(a, 2);
    a += __shfl_xor(a, 4); a += __shfl_xor(a, 8);
    if (l == 0) hs[o] = fmaxf(a + rb1[o], 0.f);
  }
  __syncthreads();
  {
    float a = rb2[tid];
#pragma unroll
    for (int j = 0; j < 8; j++) a += hs[j] * rw2[tid * 8 + j];
    ss[tid] = 1.f / (1.f + expf(-a));
  }
  __syncthreads();
  {
    float a = 0.f;
#pragma unroll
    for (int j = 0; j < 8; j++) a += ss[l * 8 + j] * rw3[o * 128 + l * 8 + j];
    a += __shfl_xor(a, 1); a += __shfl_xor(a, 2);
    a += __shfl_xor(a, 4); a += __shfl_xor(a, 8);
    if (l == 0) lg[o] = a + rb3[o];
  }
  __syncthreads();
  if (tid == 0) {
    float m = lg[0];
    for (int e = 1; e < 8; e++) m = fmaxf(m, lg[e]);
    float s = 0.f, ex[8];
    for (int e = 0; e < 8; e++) { ex[e] = expf(lg[e] - m); s += ex[e]; }
    for (int e = 0; e < 8; e++) r[b * 8 + e] = ex[e] / s;
  }
}

// ---------------- k_combine2: wr bf16 + fused pooled-output p ----------------
__global__ __launch_bounds__(256) void k_combine2(const float* __restrict__ experts,
                                                  const float* __restrict__ r,
                                                  const float* __restrict__ Sr,
                                                  __hip_bfloat16* __restrict__ wr,
                                                  float* __restrict__ p) {
  int co = blockIdx.x & 255, g = blockIdx.x >> 8;
  int tid = threadIdx.x;
  __shared__ float els[8][1152];   // 36864 B
  __shared__ float rsh[32][8];
  __shared__ float pw[4];
#pragma unroll
  for (int it = 0; it < 9; it++) {
    int f = it * 256 + tid;        // [0,2304) float4s
    int e = f / 288, q = f - e * 288;
    float4 ev = *(const float4*)(experts + (size_t)e * 294912 + (size_t)co * 1152 + q * 4);
    *(float4*)&els[e][q * 4] = ev;
  }
  rsh[tid >> 3][tid & 7] = r[tid];
  __syncthreads();
  int s = tid >> 7, ci = tid & 127;
  for (int bb = 0; bb < 4; bb++) {
    int b = g * 8 + bb * 2 + s;
    float rv[8];
#pragma unroll
    for (int e = 0; e < 8; e++) rv[e] = rsh[b][e];
    float pacc = 0.f;
    __hip_bfloat16* wrow = wr + (size_t)(b * 256 + co) * KK;
    const float* sb = Sr + b * KK;
#pragma unroll
    for (int k = 0; k < 9; k++) {
      float v = 0.f;
#pragma unroll
      for (int e = 0; e < 8; e++) v += rv[e] * els[e][ci * 9 + k];
      wrow[k * 128 + ci] = __float2bfloat16(v);
      pacc += v * sb[k * 128 + ci];
    }
    for (int off = 32; off; off >>= 1) pacc += __shfl_down(pacc, off);
    if ((tid & 63) == 0) pw[tid >> 6] = pacc;
    __syncthreads();
    if (ci == 0) p[b * 256 + co] = pw[s * 2] + pw[s * 2 + 1];
    __syncthreads();
  }
}

// ---------------- k_catt2: channel attention (parallel dots) ----------------
__global__ __launch_bounds__(256) void k_catt2(const float* __restrict__ p,
    const float* __restrict__ aw1, const float* __restrict__ ab1,
    const float* __restrict__ aw2, const float* __restrict__ ab2,
    float* __restrict__ ca) {
  int b = blockIdx.x, tid = threadIdx.x;
  int o = tid >> 4, l = tid & 15;
  __shared__ float ps[256], ts[16];
  ps[tid] = p[b * 256 + tid];
  __syncthreads();
  {
    float a = 0.f;
#pragma unroll
    for (int j = 0; j < 16; j++) a += ps[l * 16 + j] * aw1[o * 256 + l * 16 + j];
    a += __shfl_xor(a, 1); a += __shfl_xor(a, 2);
    a += __shfl_xor(a, 4); a += __shfl_xor(a, 8);
    if (l == 0) ts[o] = fmaxf(a + ab1[o], 0.f);
  }
  __syncthreads();
  float a = ab2[tid];
#pragma unroll
  for (int j = 0; j < 16; j++) a += ts[j] * aw2[tid * 16 + j];
  ca[b * 256 + tid] = 1.f / (1.f + expf(-a));
}

// ---------------- k_conv2p: 256x256 tile, 2-phase prefetch conv ----------------
// Tile: M=256 co x N=256 pos (4 rows y0..y0+3), BK=64, 18 K-tiles.
// 8 waves (wm = w>>2: 2 M-halves of 128; wn = w&3: 4 N-strips of 64).
// Per wave: acc[8][4] 16x16 frags (acc[mh*4+i2][nh*2+j2]).
// LDS: As/Bs [2 buf][256 rows][64 u16], 16B-chunk XOR swizzle (c ^ row&7),
// both-sides (pre-swizzled global source + XOR'd read offset).
// Loop: { if (t<17) stage(t+1 -> buf[(t+1)&1]);  compute(t from buf[t&1],
//         64 MFMA, no internal barriers);  __syncthreads(); }
// __syncthreads() drains vmcnt(0)+lgkmcnt(0) (compiler-emitted) => staged
// data visible; stage/compute touch opposite buffers => WAR-safe.
__global__ __launch_bounds__(512, 2) void k_conv2p(const u16* __restrict__ xt,
                                                   const u16* __restrict__ wr,
                                                   const float* __restrict__ ca,
                                                   const u16* __restrict__ zp,
                                                   float* __restrict__ out) {
  __shared__ __align__(16) u16 As[2 * 16384];  // 64 KB: [buf][256 co][64 k]
  __shared__ __align__(16) u16 Bs[2 * 16384];  // 64 KB: [buf][256 pos][64 k]

  int id = blockIdx.x;
  int swz = (id & 7) * 64 + (id >> 3);         // XCD-contiguous, bijective (512%8==0)
  int b = swz >> 4, posT = swz & 15;
  int y0 = posT * 4;

  int tid = threadIdx.x;
  int w = tid >> 6, lane = tid & 63;
  int wm = w >> 2, wn = w & 3;
  int quad = lane >> 4, l15 = lane & 15;

  // staging per-thread constants (rowT = row within 64-row quarter)
  int rowT = tid >> 3;                         // 0..63
  int srcChunk = (tid & 7) ^ (rowT & 7);       // pre-swizzled source 16B chunk
  int ldsOff = tid * 8;                        // u16 units = wave base + lane*16B
  const u16* aBase = wr + (size_t)b * (256 * KK) + (size_t)rowT * KK + srcChunk * 8;
  const u16* xtB = xt + ((size_t)b << 19);
  const u16* zpS = zp + srcChunk * 8;

  // fragment read offsets (u16 units); row&7 == l15&7 for all frag rows
  int aRow[4], bRow[2];
#pragma unroll
  for (int i2 = 0; i2 < 4; i2++) aRow[i2] = (wm * 128 + i2 * 16 + l15) << 6;
#pragma unroll
  for (int j2 = 0; j2 < 2; j2++) bRow[j2] = (wn * 64 + j2 * 16 + l15) << 6;
  int chA0 = (quad ^ (l15 & 7)) << 3;
  int chA1 = ((4 ^ quad) ^ (l15 & 7)) << 3;

  floatx4 acc[8][4];
#pragma unroll
  for (int i = 0; i < 8; i++)
#pragma unroll
    for (int j = 0; j < 4; j++) acc[i][j] = floatx4{0.f, 0.f, 0.f, 0.f};

  // stage A quarter q (co rows q*64..q*64+63) of K-tile ktS into buffer bufL
  auto SA = [&](int q, int ktS, int bufL) {
    gload_lds16(aBase + (size_t)q * (64 * KK) + ktS * 64,
                &As[(bufL << 14) + (q << 12) + ldsOff]);
  };
  // stage B quarter q (pos row y0+q, x=0..63) of K-tile ktS (halo via zero page)
  auto SB = [&](int q, int ktS, int bufL) {
    int kidx = ktS >> 1;
    int ky = (kidx * 11) >> 5;                 // kidx/3 for 0..8
    int kx = kidx - ky * 3;
    int ys = y0 + q + ky - 1;
    int xs = rowT + kx - 1;
    const u16* src = (((unsigned)ys < 64u) && ((unsigned)xs < 64u))
        ? xtB + (((size_t)(ys * 64 + xs)) << 7) + ((ktS & 1) << 6) + srcChunk * 8
        : zpS;
    gload_lds16(src, &Bs[(bufL << 14) + (q << 12) + ldsOff]);
  };

  // ---- prologue: stage tile 0 into buf0 ----
  SA(0, 0, 0); SA(1, 0, 0); SA(2, 0, 0); SA(3, 0, 0);
  SB(0, 0, 0); SB(1, 0, 0); SB(2, 0, 0); SB(3, 0, 0);
  __syncthreads();   // compiler emits s_waitcnt vmcnt(0) lgkmcnt(0) before barrier

  // ---- main loop: one __syncthreads per K-tile ----
  for (int t = 0; t < 18; t++) {
    int cur = t & 1;
    if (t < 17) {
      int nxt = cur ^ 1;
      SA(0, t + 1, nxt); SA(1, t + 1, nxt); SA(2, t + 1, nxt); SA(3, t + 1, nxt);
      SB(0, t + 1, nxt); SB(1, t + 1, nxt); SB(2, t + 1, nxt); SB(3, t + 1, nxt);
    }
    int cb = cur << 14;
    bf16x8 af[4][2], bv0[2][2], bv1[2][2];
    // ---- mh = 0 ----
#pragma unroll
    for (int i2 = 0; i2 < 4; i2++) {
      af[i2][0] = *(const bf16x8*)&As[cb + aRow[i2] + chA0];
      af[i2][1] = *(const bf16x8*)&As[cb + aRow[i2] + chA1];
    }
#pragma unroll
    for (int j2 = 0; j2 < 2; j2++) {
      bv0[j2][0] = *(const bf16x8*)&Bs[cb + bRow[j2] + chA0];
      bv0[j2][1] = *(const bf16x8*)&Bs[cb + bRow[j2] + chA1];
      bv1[j2][0] = *(const bf16x8*)&Bs[cb + bRow[j2] + (1 << 11) + chA0];
      bv1[j2][1] = *(const bf16x8*)&Bs[cb + bRow[j2] + (1 << 11) + chA1];
    }
#pragma unroll
    for (int i2 = 0; i2 < 4; i2++)
#pragma unroll
      for (int j2 = 0; j2 < 2; j2++) {
        acc[i2][j2] = __builtin_amdgcn_mfma_f32_16x16x32_bf16(af[i2][0], bv0[j2][0], acc[i2][j2], 0, 0, 0);
        acc[i2][j2] = __builtin_amdgcn_mfma_f32_16x16x32_bf16(af[i2][1], bv0[j2][1], acc[i2][j2], 0, 0, 0);
        acc[i2][2 + j2] = __builtin_amdgcn_mfma_f32_16x16x32_bf16(af[i2][0], bv1[j2][0], acc[i2][2 + j2], 0, 0, 0);
        acc[i2][2 + j2] = __builtin_amdgcn_mfma_f32_16x16x32_bf16(af[i2][1], bv1[j2][1], acc[i2][2 + j2], 0, 0, 0);
      }
    // ---- mh = 1 ----
#pragma unroll
    for (int i2 = 0; i2 < 4; i2++) {
      af[i2][0] = *(const bf16x8*)&As[cb + aRow[i2] + (1 << 12) + chA0];
      af[i2][1] = *(const bf16x8*)&As[cb + aRow[i2] + (1 << 12) + chA1];
    }
#pragma unroll
    for (int i2 = 0; i2 < 4; i2++)
#pragma unroll
      for (int j2 = 0; j2 < 2; j2++) {
        acc[4 + i2][j2] = __builtin_amdgcn_mfma_f32_16x16x32_bf16(af[i2][0], bv0[j2][0], acc[4 + i2][j2], 0, 0, 0);
        acc[4 + i2][j2] = __builtin_amdgcn_mfma_f32_16x16x32_bf16(af[i2][1], bv0[j2][1], acc[4 + i2][j2], 0, 0, 0);
        acc[4 + i2][2 + j2] = __builtin_amdgcn_mfma_f32_16x16x32_bf16(af[i2][0], bv1[j2][0], acc[4 + i2][2 + j2], 0, 0, 0);
        acc[4 + i2][2 + j2] = __builtin_amdgcn_mfma_f32_16x16x32_bf16(af[i2][1], bv1[j2][1], acc[4 + i2][2 + j2], 0, 0, 0);
      }
    asm volatile("s_waitcnt vmcnt(0)" ::: "memory");  // insurance; __syncthreads also drains
    __syncthreads();
  }

  // ---- epilogue: out[b][co][pos] = acc * ca[b][co] ----
  const float* caB = ca + b * 256 + wm * 128 + quad * 4;
  float cav[8][4];
#pragma unroll
  for (int mf = 0; mf < 8; mf++)
#pragma unroll
    for (int ri = 0; ri < 4; ri++) cav[mf][ri] = caB[mf * 16 + ri];
  float* outB = out + ((size_t)b << 20) + ((size_t)(wm * 128 + quad * 4) << 12)
              + posT * 256 + wn * 64 + l15;
#pragma unroll
  for (int mf = 0; mf < 8; mf++) {
#pragma unroll
    for (int nf = 0; nf < 4; nf++) {
#pragma unroll
      for (int ri = 0; ri < 4; ri++) {
        outB[(((size_t)(mf * 16 + ri)) << 12) + nf * 16] = acc[mf][nf][ri] * cav[mf][ri];
      }
    }
  }
}

// ---------------- host launch ----------------
extern "C" void kernel_launch(void* const* d_in, const int* in_sizes, int n_in,
                              void* d_out, int out_size, void* d_ws, size_t ws_size,
                              hipStream_t stream) {
  const float* x       = (const float*)d_in[0];
  const float* experts = (const float*)d_in[1];
  const float* rw1 = (const float*)d_in[2];
  const float* rb1 = (const float*)d_in[3];
  const float* rw2 = (const float*)d_in[4];
  const float* rb2 = (const float*)d_in[5];
  const float* rw3 = (const float*)d_in[6];
  const float* rb3 = (const float*)d_in[7];
  const float* aw1 = (const float*)d_in[8];
  const float* ab1 = (const float*)d_in[9];
  const float* aw2 = (const float*)d_in[10];
  const float* ab2 = (const float*)d_in[11];

  char* ws = (char*)d_ws;
  u16*   xt     = (u16*)(ws + 0);              // 33,554,432 B : NHWC bf16
  __hip_bfloat16* wr = (__hip_bfloat16*)(ws + 33554432);  // 18,874,368 B
  float* Sr     = (float*)(ws + 52428800);     // 147,456 B
  float* pooled = (float*)(ws + 52576256);     // 16,384 B
  float* r      = (float*)(ws + 52592640);     // 1,024 B
  float* p      = (float*)(ws + 52593664);     // 32,768 B
  float* ca     = (float*)(ws + 52626432);     // 32,768 B
  u16*   zp     = (u16*)(ws + 52659200);       // 256 B zero page

  k_stats2<<<4096, 256, 0, stream>>>(x, Sr, pooled, (unsigned*)zp);
  k_xform<<<2048, 256, 0, stream>>>(x, xt);
  k_route2<<<32, 128, 0, stream>>>(pooled, rw1, rb1, rw2, rb2, rw3, rb3, r);
  k_combine2<<<1024, 256, 0, stream>>>(experts, r, Sr, wr, p);
  k_catt2<<<32, 256, 0, stream>>>(p, aw1, ab1, aw2, ab2, ca);
  k_conv2p<<<512, 512, 0, stream>>>(xt, (const u16*)wr, ca, zp, (float*)d_out);
}

// Round 4
// 313.927 us; speedup vs baseline: 1.0228x; 1.0228x over previous
//
#include <hip/hip_runtime.h>
#include <hip/hip_bf16.h>

// EnhancedCondConv2d: B=32, CI=128, CO=256, H=W=64, E=8, R=16, K=3
// R8: front-end fusion + proven R4 conv.
//   - k_prep: single pass over x does NCHW->NHWC bf16 (xform) AND stats
//     partials (row sums via 16-lane shfl, col edges, corners) with fp32
//     atomics into scratch overlaying the wr region (dead until combine).
//   - k_statsfin: finalizes pooled/Sr from partials, then runs the whole
//     routing SE (old k_route2 body) in the same 128-thread block.
//   - k_combine2 / k_catt2 / k_conv identical to R4 (k_conv = best-known,
//     99.4 us, 2048x256, 128x128 tile, BK=64).
// Launches 6 -> 5; x read once instead of twice (-67 MB/iter).

#define BB 32
#define CI_ 128
#define CO_ 256
#define HW_ 4096
#define KK 1152   // CI*9

typedef unsigned short u16;
typedef __attribute__((ext_vector_type(8))) __bf16 bf16x8;
typedef __attribute__((ext_vector_type(4))) float floatx4;

typedef const __attribute__((address_space(1))) void* gptr_t;
typedef __attribute__((address_space(3))) void* sptr_t;

__device__ __forceinline__ void gload_lds16(const void* g, void* s) {
  __builtin_amdgcn_global_load_lds((gptr_t)g, (sptr_t)s, 16, 0, 0);
}

// ---------------- k_prep: fused xform + stats partials ----------------
// grid = 2048 (b*64+y), 256 thr. Reads x row (128 ci x 64 x f32), writes
// xt NHWC bf16 row, and accumulates per-(b,ci): T (plane sum), C0 (col-0
// sum), C63 (col-63 sum) via atomics; R0/R63 (row 0/63 sums) and corners
// stored directly by the y==0 / y==63 blocks.
__global__ __launch_bounds__(256) void k_prep(const float* __restrict__ x,
                                              u16* __restrict__ xt,
                                              float* __restrict__ Tb,
                                              float* __restrict__ C0a,
                                              float* __restrict__ C63a,
                                              float* __restrict__ R0a,
                                              float* __restrict__ R63a,
                                              float* __restrict__ CNa) {
  int blk = blockIdx.x;          // b*64 + y
  int b = blk >> 6, y = blk & 63;
  __shared__ u16 ts[64][132];
  int tid = threadIdx.x;
  const float* xb = x + ((size_t)b << 19) + (y << 6);
#pragma unroll
  for (int it = 0; it < 8; it++) {
    int idx = it * 256 + tid;
    int ci = idx >> 4, x4 = idx & 15;
    float4 v = *(const float4*)(xb + (size_t)ci * 4096 + x4 * 4);
    // ---- stats partials: 16 lanes per ci (consecutive, same wave) ----
    float rs = v.x + v.y + v.z + v.w;
    rs += __shfl_xor(rs, 1); rs += __shfl_xor(rs, 2);
    rs += __shfl_xor(rs, 4); rs += __shfl_xor(rs, 8);
    float ce = __shfl(v.w, 15, 16);          // x[b,ci,y,63]
    if (x4 == 0) {                            // this lane holds x[b,ci,y,0]=v.x
      int o = b * 128 + ci;
      atomicAdd(&Tb[o], rs);
      atomicAdd(&C0a[o], v.x);
      atomicAdd(&C63a[o], ce);
      if (y == 0)  { R0a[o]  = rs; CNa[o * 4 + 0] = v.x; CNa[o * 4 + 1] = ce; }
      if (y == 63) { R63a[o] = rs; CNa[o * 4 + 2] = v.x; CNa[o * 4 + 3] = ce; }
    }
    // ---- xform: f32 -> bf16 into LDS transpose tile ----
    __hip_bfloat16 h0 = __float2bfloat16(v.x), h1 = __float2bfloat16(v.y);
    __hip_bfloat16 h2 = __float2bfloat16(v.z), h3 = __float2bfloat16(v.w);
    int xx = x4 << 2;
    ts[xx + 0][ci] = *(const u16*)&h0;
    ts[xx + 1][ci] = *(const u16*)&h1;
    ts[xx + 2][ci] = *(const u16*)&h2;
    ts[xx + 3][ci] = *(const u16*)&h3;
  }
  __syncthreads();
  uint2* ot = (uint2*)(xt + ((size_t)b * HW_ + y * 64) * CI_);
#pragma unroll
  for (int it = 0; it < 8; it++) {
    int o = it * 256 + tid;
    int pix = o >> 5, c4 = o & 31;
    ot[o] = *(const uint2*)&ts[pix][c4 * 4];
  }
}

// ---------------- k_statsfin: Sr finalize + routing SE -> softmax ----------------
// grid = 32 (b), 128 thr (tid = ci).
__global__ __launch_bounds__(128) void k_statsfin(const float* __restrict__ Tb,
    const float* __restrict__ C0a, const float* __restrict__ C63a,
    const float* __restrict__ R0a, const float* __restrict__ R63a,
    const float* __restrict__ CNa,
    float* __restrict__ Sr,
    const float* __restrict__ rw1, const float* __restrict__ rb1,
    const float* __restrict__ rw2, const float* __restrict__ rb2,
    const float* __restrict__ rw3, const float* __restrict__ rb3,
    float* __restrict__ r) {
  int b = blockIdx.x, tid = threadIdx.x;
  int o = b * 128 + tid;
  float T   = Tb[o];
  float r0  = R0a[o],  r63 = R63a[o];
  float c0  = C0a[o],  c63 = C63a[o];
  float cn[4];
  cn[0] = CNa[o * 4 + 0]; cn[1] = CNa[o * 4 + 1];
  cn[2] = CNa[o * 4 + 2]; cn[3] = CNa[o * 4 + 3];
  __shared__ float ps[128], hs[8], ss[128], lg[8];
  ps[tid] = T * (1.0f / 4096.0f);
#pragma unroll
  for (int ky = 0; ky < 3; ky++) {
#pragma unroll
    for (int kx = 0; kx < 3; kx++) {
      int dy = ky - 1, dx = kx - 1;
      float s = T;
      if (dy == -1) s -= r63;
      if (dy ==  1) s -= r0;
      if (dx == -1) s -= c63;
      if (dx ==  1) s -= c0;
      if (dy != 0 && dx != 0) s += cn[(dy == -1 ? 2 : 0) + (dx == -1 ? 1 : 0)];
      Sr[(b * 9 + ky * 3 + kx) * CI_ + tid] = s * (1.0f / 4096.0f);
    }
  }
  __syncthreads();
  // ---- routing SE (old k_route2 body) ----
  int oo = tid >> 4, l = tid & 15;
  {
    float a = 0.f;
#pragma unroll
    for (int j = 0; j < 8; j++) a += ps[l * 8 + j] * rw1[oo * 128 + l * 8 + j];
    a += __shfl_xor(a, 1); a += __shfl_xor(a, 2);
    a += __shfl_xor(a, 4); a += __shfl_xor(a, 8);
    if (l == 0) hs[oo] = fmaxf(a + rb1[oo], 0.f);
  }
  __syncthreads();
  {
    float a = rb2[tid];
#pragma unroll
    for (int j = 0; j < 8; j++) a += hs[j] * rw2[tid * 8 + j];
    ss[tid] = 1.f / (1.f + expf(-a));
  }
  __syncthreads();
  {
    float a = 0.f;
#pragma unroll
    for (int j = 0; j < 8; j++) a += ss[l * 8 + j] * rw3[oo * 128 + l * 8 + j];
    a += __shfl_xor(a, 1); a += __shfl_xor(a, 2);
    a += __shfl_xor(a, 4); a += __shfl_xor(a, 8);
    if (l == 0) lg[oo] = a + rb3[oo];
  }
  __syncthreads();
  if (tid == 0) {
    float m = lg[0];
    for (int e = 1; e < 8; e++) m = fmaxf(m, lg[e]);
    float s = 0.f, ex[8];
    for (int e = 0; e < 8; e++) { ex[e] = expf(lg[e] - m); s += ex[e]; }
    for (int e = 0; e < 8; e++) r[b * 8 + e] = ex[e] / s;
  }
}

// ---------------- k_combine2: wr bf16 + fused pooled-output p ----------------
__global__ __launch_bounds__(256) void k_combine2(const float* __restrict__ experts,
                                                  const float* __restrict__ r,
                                                  const float* __restrict__ Sr,
                                                  __hip_bfloat16* __restrict__ wr,
                                                  float* __restrict__ p) {
  int co = blockIdx.x & 255, g = blockIdx.x >> 8;
  int tid = threadIdx.x;
  __shared__ float els[8][1152];   // 36864 B
  __shared__ float rsh[32][8];
  __shared__ float pw[4];
#pragma unroll
  for (int it = 0; it < 9; it++) {
    int f = it * 256 + tid;        // [0,2304) float4s
    int e = f / 288, q = f - e * 288;
    float4 ev = *(const float4*)(experts + (size_t)e * 294912 + (size_t)co * 1152 + q * 4);
    *(float4*)&els[e][q * 4] = ev;
  }
  rsh[tid >> 3][tid & 7] = r[tid];
  __syncthreads();
  int s = tid >> 7, ci = tid & 127;
  for (int bb = 0; bb < 4; bb++) {
    int b = g * 8 + bb * 2 + s;
    float rv[8];
#pragma unroll
    for (int e = 0; e < 8; e++) rv[e] = rsh[b][e];
    float pacc = 0.f;
    __hip_bfloat16* wrow = wr + (size_t)(b * 256 + co) * KK;
    const float* sb = Sr + b * KK;
#pragma unroll
    for (int k = 0; k < 9; k++) {
      float v = 0.f;
#pragma unroll
      for (int e = 0; e < 8; e++) v += rv[e] * els[e][ci * 9 + k];
      wrow[k * 128 + ci] = __float2bfloat16(v);
      pacc += v * sb[k * 128 + ci];
    }
    for (int off = 32; off; off >>= 1) pacc += __shfl_down(pacc, off);
    if ((tid & 63) == 0) pw[tid >> 6] = pacc;
    __syncthreads();
    if (ci == 0) p[b * 256 + co] = pw[s * 2] + pw[s * 2 + 1];
    __syncthreads();
  }
}

// ---------------- k_catt2: channel attention (parallel dots) ----------------
__global__ __launch_bounds__(256) void k_catt2(const float* __restrict__ p,
    const float* __restrict__ aw1, const float* __restrict__ ab1,
    const float* __restrict__ aw2, const float* __restrict__ ab2,
    float* __restrict__ ca) {
  int b = blockIdx.x, tid = threadIdx.x;
  int o = tid >> 4, l = tid & 15;
  __shared__ float ps[256], ts[16];
  ps[tid] = p[b * 256 + tid];
  __syncthreads();
  {
    float a = 0.f;
#pragma unroll
    for (int j = 0; j < 16; j++) a += ps[l * 16 + j] * aw1[o * 256 + l * 16 + j];
    a += __shfl_xor(a, 1); a += __shfl_xor(a, 2);
    a += __shfl_xor(a, 4); a += __shfl_xor(a, 8);
    if (l == 0) ts[o] = fmaxf(a + ab1[o], 0.f);
  }
  __syncthreads();
  float a = ab2[tid];
#pragma unroll
  for (int j = 0; j < 16; j++) a += ts[j] * aw2[tid * 16 + j];
  ca[b * 256 + tid] = 1.f / (1.f + expf(-a));
}

// ---------------- k_conv: implicit-GEMM MFMA conv, BK=64 (R4 verbatim) --------
// grid = 2048, XCD-swizzled: b = (id&7) + 8*((id>>9)&3) so each XCD owns 4 b.
// Block tile: M=128 co, N=128 pos (2 rows), K-loop: 9 kidx x 2 ci-halves of 64.
// LDS: As/Bs 128 rows x 64 u16 (128 B pitch), chunk swizzle p = c ^ (row&7).
__global__ __launch_bounds__(256) void k_conv(const u16* __restrict__ xt,
                                              const u16* __restrict__ wr,
                                              const float* __restrict__ ca,
                                              const u16* __restrict__ zp,
                                              float* __restrict__ out) {
  int id = blockIdx.x;
  int b = (id & 7) | (((id >> 9) & 3) << 3);
  int rem = (id >> 3) & 63;
  int coT = rem >> 5, rp = rem & 31;
  int y0 = rp * 2;
  int coBase = coT * 128;
  int tid = threadIdx.x;
  int w = tid >> 6, lane = tid & 63;
  int wm = w & 1, wn = w >> 1;
  int quad = lane >> 4, l15 = lane & 15;
  int cl8 = lane & 7, lr = lane >> 3;

  __shared__ __align__(16) u16 As[128 * 64];   // 16 KB
  __shared__ __align__(16) u16 Bs[128 * 64];   // 16 KB

  // staging: 4 rounds; round ri stages rows [ri*32 + w*8 + lr], chunk pos cl8.
  const u16* aP[4];
  int dstO[4], chB[4], ylocB[4], xlocB[4];
#pragma unroll
  for (int ri = 0; ri < 4; ri++) {
    int rr = ri * 32 + w * 8 + lr;
    int c = cl8 ^ (rr & 7);                 // source k-chunk for LDS position cl8
    aP[ri] = wr + (size_t)(b * 256 + coBase + rr) * KK + c * 8;
    dstO[ri] = rr * 64 + cl8 * 8;           // = wave-uniform base + lane*16B
    chB[ri] = c;
    ylocB[ri] = rr >> 6;
    xlocB[ri] = rr & 63;
  }

  // fragment LDS read offsets: position = (h*4+quad) ^ (m&7)
  int aOff[4][2], bOff[4][2];
#pragma unroll
  for (int i = 0; i < 4; i++) {
    int m = wm * 64 + i * 16 + l15;
    int n = wn * 64 + i * 16 + l15;
#pragma unroll
    for (int h = 0; h < 2; h++) {
      aOff[i][h] = m * 64 + ((((h << 2) | quad) ^ (m & 7)) << 3);
      bOff[i][h] = n * 64 + ((((h << 2) | quad) ^ (n & 7)) << 3);
    }
  }

  floatx4 acc[4][4];
#pragma unroll
  for (int i = 0; i < 4; i++)
#pragma unroll
    for (int j = 0; j < 4; j++) acc[i][j] = floatx4{0.f, 0.f, 0.f, 0.f};

  for (int kidx = 0; kidx < 9; kidx++) {
    int ky = kidx / 3, kx = kidx - ky * 3;
    const u16* bP[4];
    int bStep[4];
#pragma unroll
    for (int ri = 0; ri < 4; ri++) {
      int ys = y0 + ylocB[ri] + ky - 1;
      int xs = xlocB[ri] + kx - 1;
      bool valid = ((unsigned)ys < 64u) && ((unsigned)xs < 64u);
      bP[ri] = valid ? (xt + ((size_t)(b * HW_ + ys * 64 + xs) << 7) + chB[ri] * 8)
                     : (zp + chB[ri] * 8);
      bStep[ri] = valid ? 64 : 0;
    }
#pragma unroll
    for (int cib = 0; cib < 2; cib++) {
      __syncthreads();
#pragma unroll
      for (int ri = 0; ri < 4; ri++)
        gload_lds16(aP[ri] + kidx * 128 + cib * 64, &As[dstO[ri]]);
#pragma unroll
      for (int ri = 0; ri < 4; ri++)
        gload_lds16(bP[ri] + cib * bStep[ri], &Bs[dstO[ri]]);
      __syncthreads();
#pragma unroll
      for (int h = 0; h < 2; h++) {
        bf16x8 af[4], bfv[4];
#pragma unroll
        for (int i = 0; i < 4; i++) af[i] = *(const bf16x8*)&As[aOff[i][h]];
#pragma unroll
        for (int j = 0; j < 4; j++) bfv[j] = *(const bf16x8*)&Bs[bOff[j][h]];
#pragma unroll
        for (int i = 0; i < 4; i++)
#pragma unroll
          for (int j = 0; j < 4; j++)
            acc[i][j] = __builtin_amdgcn_mfma_f32_16x16x32_bf16(af[i], bfv[j], acc[i][j], 0, 0, 0);
      }
    }
  }

  // epilogue: out[b][co][y][x] = acc * ca[b][co]
  float cav[4][4];
#pragma unroll
  for (int i = 0; i < 4; i++)
#pragma unroll
    for (int ri = 0; ri < 4; ri++)
      cav[i][ri] = ca[b * 256 + coBase + wm * 64 + i * 16 + quad * 4 + ri];
#pragma unroll
  for (int i = 0; i < 4; i++) {
#pragma unroll
    for (int j = 0; j < 4; j++) {
      int n = wn * 64 + j * 16 + l15;
      int yy = y0 + (n >> 6), xx = n & 63;
#pragma unroll
      for (int ri = 0; ri < 4; ri++) {
        int co = coBase + wm * 64 + i * 16 + quad * 4 + ri;
        out[((size_t)(b * 256 + co) << 12) + (yy << 6) + xx] = acc[i][j][ri] * cav[i][ri];
      }
    }
  }
}

// ---------------- host launch ----------------
extern "C" void kernel_launch(void* const* d_in, const int* in_sizes, int n_in,
                              void* d_out, int out_size, void* d_ws, size_t ws_size,
                              hipStream_t stream) {
  const float* x       = (const float*)d_in[0];
  const float* experts = (const float*)d_in[1];
  const float* rw1 = (const float*)d_in[2];
  const float* rb1 = (const float*)d_in[3];
  const float* rw2 = (const float*)d_in[4];
  const float* rb2 = (const float*)d_in[5];
  const float* rw3 = (const float*)d_in[6];
  const float* rb3 = (const float*)d_in[7];
  const float* aw1 = (const float*)d_in[8];
  const float* ab1 = (const float*)d_in[9];
  const float* aw2 = (const float*)d_in[10];
  const float* ab2 = (const float*)d_in[11];

  char* ws = (char*)d_ws;
  u16*   xt     = (u16*)(ws + 0);              // 33,554,432 B : NHWC bf16
  __hip_bfloat16* wr = (__hip_bfloat16*)(ws + 33554432);  // 18,874,368 B
  float* Sr     = (float*)(ws + 52428800);     // 147,456 B
  float* r      = (float*)(ws + 52592640);     // 1,024 B
  float* p      = (float*)(ws + 52593664);     // 32,768 B
  float* ca     = (float*)(ws + 52626432);     // 32,768 B
  u16*   zp     = (u16*)(ws + 52659200);       // 256 B zero page

  // stats scratch overlays the wr region (dead until k_combine2 writes it,
  // which happens only after k_statsfin has consumed these):
  float* Tb   = (float*)(ws + 33554432);       // 16,384 B  (atomic, memset)
  float* C0a  = Tb + 4096;                     // 16,384 B  (atomic, memset)
  float* C63a = Tb + 8192;                     // 16,384 B  (atomic, memset)
  float* R0a  = Tb + 12288;                    // 16,384 B  (direct store)
  float* R63a = Tb + 16384;                    // 16,384 B  (direct store)
  float* CNa  = Tb + 20480;                    // 65,536 B  (direct store)

  hipMemsetAsync(Tb, 0, 3 * 16384, stream);    // zero T/C0/C63 accumulators
  hipMemsetAsync(zp, 0, 256, stream);          // zero page for conv halo

  k_prep<<<2048, 256, 0, stream>>>(x, xt, Tb, C0a, C63a, R0a, R63a, CNa);
  k_statsfin<<<32, 128, 0, stream>>>(Tb, C0a, C63a, R0a, R63a, CNa, Sr,
                                     rw1, rb1, rw2, rb2, rw3, rb3, r);
  k_combine2<<<1024, 256, 0, stream>>>(experts, r, Sr, wr, p);
  k_catt2<<<32, 256, 0, stream>>>(p, aw1, ab1, aw2, ab2, ca);
  k_conv<<<2048, 256, 0, stream>>>(xt, (const u16*)wr, ca, zp, (float*)d_out);
}

// Round 6
// 312.196 us; speedup vs baseline: 1.0285x; 1.0055x over previous
//
#include <hip/hip_runtime.h>
#include <hip/hip_bf16.h>

// EnhancedCondConv2d: B=32, CI=128, CO=256, H=W=64, E=8, R=16, K=3
// R10: R8 front-end (proven) + k_convd: R4's 128x128 conv made double-
//      buffered with ONE __syncthreads per K-step (R7's proven sync class;
//      NO raw-asm barriers — that machinery failed deterministically 3x and
//      is permanently abandoned). Stage(step s+1 -> other buf) issued BEFORE
//      compute(step s); __syncthreads drains vmcnt+lgkm. LDS 64 KB ->
//      2 blocks/CU, barriers halved (36->18), staging overlaps compute.

#define BB 32
#define CI_ 128
#define CO_ 256
#define HW_ 4096
#define KK 1152   // CI*9

typedef unsigned short u16;
typedef __attribute__((ext_vector_type(8))) __bf16 bf16x8;
typedef __attribute__((ext_vector_type(4))) float floatx4;

typedef const __attribute__((address_space(1))) void* gptr_t;
typedef __attribute__((address_space(3))) void* sptr_t;

__device__ __forceinline__ void gload_lds16(const void* g, void* s) {
  __builtin_amdgcn_global_load_lds((gptr_t)g, (sptr_t)s, 16, 0, 0);
}

// ---------------- k_prep: fused xform + stats partials ----------------
__global__ __launch_bounds__(256) void k_prep(const float* __restrict__ x,
                                              u16* __restrict__ xt,
                                              float* __restrict__ Tb,
                                              float* __restrict__ C0a,
                                              float* __restrict__ C63a,
                                              float* __restrict__ R0a,
                                              float* __restrict__ R63a,
                                              float* __restrict__ CNa) {
  int blk = blockIdx.x;          // b*64 + y
  int b = blk >> 6, y = blk & 63;
  __shared__ u16 ts[64][132];
  int tid = threadIdx.x;
  const float* xb = x + ((size_t)b << 19) + (y << 6);
#pragma unroll
  for (int it = 0; it < 8; it++) {
    int idx = it * 256 + tid;
    int ci = idx >> 4, x4 = idx & 15;
    float4 v = *(const float4*)(xb + (size_t)ci * 4096 + x4 * 4);
    float rs = v.x + v.y + v.z + v.w;
    rs += __shfl_xor(rs, 1); rs += __shfl_xor(rs, 2);
    rs += __shfl_xor(rs, 4); rs += __shfl_xor(rs, 8);
    float ce = __shfl(v.w, 15, 16);          // x[b,ci,y,63]
    if (x4 == 0) {                            // lane holds x[b,ci,y,0]=v.x
      int o = b * 128 + ci;
      atomicAdd(&Tb[o], rs);
      atomicAdd(&C0a[o], v.x);
      atomicAdd(&C63a[o], ce);
      if (y == 0)  { R0a[o]  = rs; CNa[o * 4 + 0] = v.x; CNa[o * 4 + 1] = ce; }
      if (y == 63) { R63a[o] = rs; CNa[o * 4 + 2] = v.x; CNa[o * 4 + 3] = ce; }
    }
    __hip_bfloat16 h0 = __float2bfloat16(v.x), h1 = __float2bfloat16(v.y);
    __hip_bfloat16 h2 = __float2bfloat16(v.z), h3 = __float2bfloat16(v.w);
    int xx = x4 << 2;
    ts[xx + 0][ci] = *(const u16*)&h0;
    ts[xx + 1][ci] = *(const u16*)&h1;
    ts[xx + 2][ci] = *(const u16*)&h2;
    ts[xx + 3][ci] = *(const u16*)&h3;
  }
  __syncthreads();
  uint2* ot = (uint2*)(xt + ((size_t)b * HW_ + y * 64) * CI_);
#pragma unroll
  for (int it = 0; it < 8; it++) {
    int o = it * 256 + tid;
    int pix = o >> 5, c4 = o & 31;
    ot[o] = *(const uint2*)&ts[pix][c4 * 4];
  }
}

// ---------------- k_statsfin: Sr finalize + routing SE -> softmax ------------
__global__ __launch_bounds__(128) void k_statsfin(const float* __restrict__ Tb,
    const float* __restrict__ C0a, const float* __restrict__ C63a,
    const float* __restrict__ R0a, const float* __restrict__ R63a,
    const float* __restrict__ CNa,
    float* __restrict__ Sr,
    const float* __restrict__ rw1, const float* __restrict__ rb1,
    const float* __restrict__ rw2, const float* __restrict__ rb2,
    const float* __restrict__ rw3, const float* __restrict__ rb3,
    float* __restrict__ r) {
  int b = blockIdx.x, tid = threadIdx.x;
  int o = b * 128 + tid;
  float T   = Tb[o];
  float r0  = R0a[o],  r63 = R63a[o];
  float c0  = C0a[o],  c63 = C63a[o];
  float cn[4];
  cn[0] = CNa[o * 4 + 0]; cn[1] = CNa[o * 4 + 1];
  cn[2] = CNa[o * 4 + 2]; cn[3] = CNa[o * 4 + 3];
  __shared__ float ps[128], hs[8], ss[128], lg[8];
  ps[tid] = T * (1.0f / 4096.0f);
#pragma unroll
  for (int ky = 0; ky < 3; ky++) {
#pragma unroll
    for (int kx = 0; kx < 3; kx++) {
      int dy = ky - 1, dx = kx - 1;
      float s = T;
      if (dy == -1) s -= r63;
      if (dy ==  1) s -= r0;
      if (dx == -1) s -= c63;
      if (dx ==  1) s -= c0;
      if (dy != 0 && dx != 0) s += cn[(dy == -1 ? 2 : 0) + (dx == -1 ? 1 : 0)];
      Sr[(b * 9 + ky * 3 + kx) * CI_ + tid] = s * (1.0f / 4096.0f);
    }
  }
  __syncthreads();
  int oo = tid >> 4, l = tid & 15;
  {
    float a = 0.f;
#pragma unroll
    for (int j = 0; j < 8; j++) a += ps[l * 8 + j] * rw1[oo * 128 + l * 8 + j];
    a += __shfl_xor(a, 1); a += __shfl_xor(a, 2);
    a += __shfl_xor(a, 4); a += __shfl_xor(a, 8);
    if (l == 0) hs[oo] = fmaxf(a + rb1[oo], 0.f);
  }
  __syncthreads();
  {
    float a = rb2[tid];
#pragma unroll
    for (int j = 0; j < 8; j++) a += hs[j] * rw2[tid * 8 + j];
    ss[tid] = 1.f / (1.f + expf(-a));
  }
  __syncthreads();
  {
    float a = 0.f;
#pragma unroll
    for (int j = 0; j < 8; j++) a += ss[l * 8 + j] * rw3[oo * 128 + l * 8 + j];
    a += __shfl_xor(a, 1); a += __shfl_xor(a, 2);
    a += __shfl_xor(a, 4); a += __shfl_xor(a, 8);
    if (l == 0) lg[oo] = a + rb3[oo];
  }
  __syncthreads();
  if (tid == 0) {
    float m = lg[0];
    for (int e = 1; e < 8; e++) m = fmaxf(m, lg[e]);
    float s = 0.f, ex[8];
    for (int e = 0; e < 8; e++) { ex[e] = expf(lg[e] - m); s += ex[e]; }
    for (int e = 0; e < 8; e++) r[b * 8 + e] = ex[e] / s;
  }
}

// ---------------- k_combine2: wr bf16 + fused pooled-output p ----------------
__global__ __launch_bounds__(256) void k_combine2(const float* __restrict__ experts,
                                                  const float* __restrict__ r,
                                                  const float* __restrict__ Sr,
                                                  __hip_bfloat16* __restrict__ wr,
                                                  float* __restrict__ p) {
  int co = blockIdx.x & 255, g = blockIdx.x >> 8;
  int tid = threadIdx.x;
  __shared__ float els[8][1152];   // 36864 B
  __shared__ float rsh[32][8];
  __shared__ float pw[4];
#pragma unroll
  for (int it = 0; it < 9; it++) {
    int f = it * 256 + tid;        // [0,2304) float4s
    int e = f / 288, q = f - e * 288;
    float4 ev = *(const float4*)(experts + (size_t)e * 294912 + (size_t)co * 1152 + q * 4);
    *(float4*)&els[e][q * 4] = ev;
  }
  rsh[tid >> 3][tid & 7] = r[tid];
  __syncthreads();
  int s = tid >> 7, ci = tid & 127;
  for (int bb = 0; bb < 4; bb++) {
    int b = g * 8 + bb * 2 + s;
    float rv[8];
#pragma unroll
    for (int e = 0; e < 8; e++) rv[e] = rsh[b][e];
    float pacc = 0.f;
    __hip_bfloat16* wrow = wr + (size_t)(b * 256 + co) * KK;
    const float* sb = Sr + b * KK;
#pragma unroll
    for (int k = 0; k < 9; k++) {
      float v = 0.f;
#pragma unroll
      for (int e = 0; e < 8; e++) v += rv[e] * els[e][ci * 9 + k];
      wrow[k * 128 + ci] = __float2bfloat16(v);
      pacc += v * sb[k * 128 + ci];
    }
    for (int off = 32; off; off >>= 1) pacc += __shfl_down(pacc, off);
    if ((tid & 63) == 0) pw[tid >> 6] = pacc;
    __syncthreads();
    if (ci == 0) p[b * 256 + co] = pw[s * 2] + pw[s * 2 + 1];
    __syncthreads();
  }
}

// ---------------- k_catt2: channel attention (parallel dots) ----------------
__global__ __launch_bounds__(256) void k_catt2(const float* __restrict__ p,
    const float* __restrict__ aw1, const float* __restrict__ ab1,
    const float* __restrict__ aw2, const float* __restrict__ ab2,
    float* __restrict__ ca) {
  int b = blockIdx.x, tid = threadIdx.x;
  int o = tid >> 4, l = tid & 15;
  __shared__ float ps[256], ts[16];
  ps[tid] = p[b * 256 + tid];
  __syncthreads();
  {
    float a = 0.f;
#pragma unroll
    for (int j = 0; j < 16; j++) a += ps[l * 16 + j] * aw1[o * 256 + l * 16 + j];
    a += __shfl_xor(a, 1); a += __shfl_xor(a, 2);
    a += __shfl_xor(a, 4); a += __shfl_xor(a, 8);
    if (l == 0) ts[o] = fmaxf(a + ab1[o], 0.f);
  }
  __syncthreads();
  float a = ab2[tid];
#pragma unroll
  for (int j = 0; j < 16; j++) a += ts[j] * aw2[tid * 16 + j];
  ca[b * 256 + tid] = 1.f / (1.f + expf(-a));
}

// ---------------- k_convd: 128x128 implicit-GEMM conv, double-buffered ------
// R4's exact grid/indexing/fragments/epilogue; LDS doubled to [2][128][64],
// one __syncthreads per K-step: { stage(s+1 -> buf nxt); compute(s, buf cur);
// __syncthreads(); }. Steps s = kidx*2+cib: even body (cib=0, buf0) stages
// (kidx, cib=1)->buf1 with current bP; odd body (cib=1, buf1) recomputes bP
// for kidx+1 and stages (kidx+1, 0)->buf0. __syncthreads drains vmcnt+lgkm:
// staged data visible next step; stage/compute touch opposite buffers.
__global__ __launch_bounds__(256) void k_convd(const u16* __restrict__ xt,
                                               const u16* __restrict__ wr,
                                               const float* __restrict__ ca,
                                               const u16* __restrict__ zp,
                                               float* __restrict__ out) {
  int id = blockIdx.x;
  int b = (id & 7) | (((id >> 9) & 3) << 3);
  int rem = (id >> 3) & 63;
  int coT = rem >> 5, rp = rem & 31;
  int y0 = rp * 2;
  int coBase = coT * 128;
  int tid = threadIdx.x;
  int w = tid >> 6, lane = tid & 63;
  int wm = w & 1, wn = w >> 1;
  int quad = lane >> 4, l15 = lane & 15;
  int cl8 = lane & 7, lr = lane >> 3;

  __shared__ __align__(16) u16 As[2 * 8192];   // 32 KB: [buf][128 co][64 k]
  __shared__ __align__(16) u16 Bs[2 * 8192];   // 32 KB: [buf][128 pos][64 k]

  // staging constants (R4 verbatim)
  const u16* aP[4];
  int dstO[4], chB[4], ylocB[4], xlocB[4];
#pragma unroll
  for (int ri = 0; ri < 4; ri++) {
    int rr = ri * 32 + w * 8 + lr;
    int c = cl8 ^ (rr & 7);                 // source k-chunk for LDS position cl8
    aP[ri] = wr + (size_t)(b * 256 + coBase + rr) * KK + c * 8;
    dstO[ri] = rr * 64 + cl8 * 8;           // wave-uniform base + lane*16B
    chB[ri] = c;
    ylocB[ri] = rr >> 6;
    xlocB[ri] = rr & 63;
  }

  // fragment LDS read offsets (R4 verbatim)
  int aOff[4][2], bOff[4][2];
#pragma unroll
  for (int i = 0; i < 4; i++) {
    int m = wm * 64 + i * 16 + l15;
    int n = wn * 64 + i * 16 + l15;
#pragma unroll
    for (int h = 0; h < 2; h++) {
      aOff[i][h] = m * 64 + ((((h << 2) | quad) ^ (m & 7)) << 3);
      bOff[i][h] = n * 64 + ((((h << 2) | quad) ^ (n & 7)) << 3);
    }
  }

  floatx4 acc[4][4];
#pragma unroll
  for (int i = 0; i < 4; i++)
#pragma unroll
    for (int j = 0; j < 4; j++) acc[i][j] = floatx4{0.f, 0.f, 0.f, 0.f};

  // B pointers for current kidx (R4 formula)
  const u16* bP[4];
  int bStep[4];
  auto setBP = [&](int kidx) {
    int ky = (kidx * 11) >> 5;               // kidx/3 for 0..8
    int kx = kidx - ky * 3;
#pragma unroll
    for (int ri = 0; ri < 4; ri++) {
      int ys = y0 + ylocB[ri] + ky - 1;
      int xs = xlocB[ri] + kx - 1;
      bool valid = ((unsigned)ys < 64u) && ((unsigned)xs < 64u);
      bP[ri] = valid ? (xt + ((size_t)(b * HW_ + ys * 64 + xs) << 7) + chB[ri] * 8)
                     : (zp + chB[ri] * 8);
      bStep[ri] = valid ? 64 : 0;
    }
  };

  // compute from buffer bufC (compile-time 0/1), fragments R4 verbatim
  auto compute = [&](int bufC) {
    int cb = bufC << 13;                     // 8192 u16 per buffer
#pragma unroll
    for (int h = 0; h < 2; h++) {
      bf16x8 af[4], bfv[4];
#pragma unroll
      for (int i = 0; i < 4; i++) af[i] = *(const bf16x8*)&As[cb + aOff[i][h]];
#pragma unroll
      for (int j = 0; j < 4; j++) bfv[j] = *(const bf16x8*)&Bs[cb + bOff[j][h]];
#pragma unroll
      for (int i = 0; i < 4; i++)
#pragma unroll
        for (int j = 0; j < 4; j++)
          acc[i][j] = __builtin_amdgcn_mfma_f32_16x16x32_bf16(af[i], bfv[j], acc[i][j], 0, 0, 0);
    }
  };

  // ---- prologue: stage (kidx=0, cib=0) -> buf0 ----
  setBP(0);
#pragma unroll
  for (int ri = 0; ri < 4; ri++) gload_lds16(aP[ri], &As[dstO[ri]]);
#pragma unroll
  for (int ri = 0; ri < 4; ri++) gload_lds16(bP[ri], &Bs[dstO[ri]]);
  __syncthreads();   // drains vmcnt(0) lgkmcnt(0)

  // ---- main loop: 9 iterations x {even step (cib0,buf0), odd step (cib1,buf1)}
  for (int kidx = 0; kidx < 9; kidx++) {
    // even: stage (kidx, cib=1) -> buf1, compute (kidx, cib=0) from buf0
#pragma unroll
    for (int ri = 0; ri < 4; ri++)
      gload_lds16(aP[ri] + kidx * 128 + 64, &As[8192 + dstO[ri]]);
#pragma unroll
    for (int ri = 0; ri < 4; ri++)
      gload_lds16(bP[ri] + bStep[ri], &Bs[8192 + dstO[ri]]);
    compute(0);
    __syncthreads();
    // odd: stage (kidx+1, cib=0) -> buf0 (if any), compute (kidx,1) from buf1
    if (kidx < 8) {
      setBP(kidx + 1);
#pragma unroll
      for (int ri = 0; ri < 4; ri++)
        gload_lds16(aP[ri] + (kidx + 1) * 128, &As[dstO[ri]]);
#pragma unroll
      for (int ri = 0; ri < 4; ri++)
        gload_lds16(bP[ri], &Bs[dstO[ri]]);
    }
    compute(1);
    __syncthreads();
  }

  // epilogue: out[b][co][y][x] = acc * ca[b][co] (R4 verbatim)
  float cav[4][4];
#pragma unroll
  for (int i = 0; i < 4; i++)
#pragma unroll
    for (int ri = 0; ri < 4; ri++)
      cav[i][ri] = ca[b * 256 + coBase + wm * 64 + i * 16 + quad * 4 + ri];
#pragma unroll
  for (int i = 0; i < 4; i++) {
#pragma unroll
    for (int j = 0; j < 4; j++) {
      int n = wn * 64 + j * 16 + l15;
      int yy = y0 + (n >> 6), xx = n & 63;
#pragma unroll
      for (int ri = 0; ri < 4; ri++) {
        int co = coBase + wm * 64 + i * 16 + quad * 4 + ri;
        out[((size_t)(b * 256 + co) << 12) + (yy << 6) + xx] = acc[i][j][ri] * cav[i][ri];
      }
    }
  }
}

// ---------------- host launch ----------------
extern "C" void kernel_launch(void* const* d_in, const int* in_sizes, int n_in,
                              void* d_out, int out_size, void* d_ws, size_t ws_size,
                              hipStream_t stream) {
  const float* x       = (const float*)d_in[0];
  const float* experts = (const float*)d_in[1];
  const float* rw1 = (const float*)d_in[2];
  const float* rb1 = (const float*)d_in[3];
  const float* rw2 = (const float*)d_in[4];
  const float* rb2 = (const float*)d_in[5];
  const float* rw3 = (const float*)d_in[6];
  const float* rb3 = (const float*)d_in[7];
  const float* aw1 = (const float*)d_in[8];
  const float* ab1 = (const float*)d_in[9];
  const float* aw2 = (const float*)d_in[10];
  const float* ab2 = (const float*)d_in[11];

  char* ws = (char*)d_ws;
  u16*   xt     = (u16*)(ws + 0);              // 33,554,432 B : NHWC bf16
  __hip_bfloat16* wr = (__hip_bfloat16*)(ws + 33554432);  // 18,874,368 B
  float* Sr     = (float*)(ws + 52428800);     // 147,456 B
  float* r      = (float*)(ws + 52592640);     // 1,024 B
  float* p      = (float*)(ws + 52593664);     // 32,768 B
  float* ca     = (float*)(ws + 52626432);     // 32,768 B
  u16*   zp     = (u16*)(ws + 52659200);       // 256 B zero page

  // stats scratch overlays the wr region (dead until k_combine2):
  float* Tb   = (float*)(ws + 33554432);       // atomic, memset
  float* C0a  = Tb + 4096;
  float* C63a = Tb + 8192;
  float* R0a  = Tb + 12288;
  float* R63a = Tb + 16384;
  float* CNa  = Tb + 20480;

  hipMemsetAsync(Tb, 0, 3 * 16384, stream);    // zero T/C0/C63 accumulators
  hipMemsetAsync(zp, 0, 256, stream);          // zero page for conv halo

  k_prep<<<2048, 256, 0, stream>>>(x, xt, Tb, C0a, C63a, R0a, R63a, CNa);
  k_statsfin<<<32, 128, 0, stream>>>(Tb, C0a, C63a, R0a, R63a, CNa, Sr,
                                     rw1, rb1, rw2, rb2, rw3, rb3, r);
  k_combine2<<<1024, 256, 0, stream>>>(experts, r, Sr, wr, p);
  k_catt2<<<32, 256, 0, stream>>>(p, aw1, ab1, aw2, ab2, ca);
  k_convd<<<2048, 256, 0, stream>>>(xt, (const u16*)wr, ca, zp, (float*)d_out);
}